// Round 2
// baseline (157.335 us; speedup 1.0000x reference)
//
#include <hip/hip_runtime.h>
#include <stdint.h>

#define VOCAB 21128
#define NUMC  53
#define EMB   128
#define SEQ   512
#define BATCH 512

typedef __bf16 bf16x8 __attribute__((ext_vector_type(8)));
typedef float f32x4 __attribute__((ext_vector_type(4)));

__device__ __forceinline__ unsigned int f2bf1(float f) {
    union { float f; unsigned int u; } v; v.f = f;
    return (v.u + 0x7FFFu + ((v.u >> 16) & 1u)) >> 16;
}
__device__ __forceinline__ unsigned int pack2(float a, float b) {
    return f2bf1(a) | (f2bf1(b) << 16);
}

// Prep: emb_table fp32 -> bf16 Tb[VOCAB][128] (vectorized, 8 elem/thread);
// conv_w -> Wp bf16 in per-lane B-fragment order:
// Wp[s 0..11][g 0..7][lane 0..63][j 0..7] = w[f=g*16+(lane&15)][e=kk&127][tap=kk>>7],
// kk = s*32 + (lane>>4)*8 + j
__global__ void prep_kernel(const float* __restrict__ emb, const float* __restrict__ cw,
                            unsigned short* __restrict__ Tb, unsigned short* __restrict__ Wp) {
    int idx = blockIdx.x * blockDim.x + threadIdx.x;
    const int n8 = VOCAB * EMB / 8;  // 338048
    if (idx < n8) {
        const float4* src = (const float4*)emb + (size_t)idx * 2;
        float4 a = src[0], b = src[1];
        uint4 o;
        o.x = pack2(a.x, a.y);
        o.y = pack2(a.z, a.w);
        o.z = pack2(b.x, b.y);
        o.w = pack2(b.z, b.w);
        *(uint4*)(Tb + (size_t)idx * 8) = o;
    }
    if (idx < 12 * 8 * 64 * 8) {
        int j = idx & 7, l = (idx >> 3) & 63, g = (idx >> 9) & 7, s = idx >> 12;
        int kk = s * 32 + (l >> 4) * 8 + j;
        int f = g * 16 + (l & 15);
        int tap = kk >> 7, e = kk & 127;
        Wp[idx] = (unsigned short)f2bf1(cw[(f * EMB + e) * 3 + tap]);
    }
}

// One block per batch row. 512 threads = 8 waves, wave w: wm=w&1 (64-pos half),
// wn=w>>1 (32-filter quarter). 4 l-tiles of 128 positions, double-buffered LDS
// with register prefetch of the next tile's gather issued BEFORE the MFMA loop.
__launch_bounds__(512, 4)
__global__ void pcnn_main(const int* __restrict__ cid, const int* __restrict__ p1,
                          const int* __restrict__ p2,
                          const unsigned short* __restrict__ Tb,
                          const unsigned short* __restrict__ Wp,
                          const float* __restrict__ cb, const float* __restrict__ fcw,
                          const float* __restrict__ fcb, float* __restrict__ out) {
    // x-tile: 130 rows (1-halo) x 128 emb bf16, rows padded to 136 hw (272 B)
    __shared__ __align__(16) unsigned short xs[2][130 * 136];  // 2 x 35,360 B
    __shared__ unsigned int sid[514];                          // id*256 byte offsets, OOB->row 0 (zeros)
    __shared__ float pstage[2][3][128];                        // 3,072 B
    __shared__ float pooled[384];
    __shared__ float fcred[NUMC][4];
    // total ~78.2 KB -> 2 blocks/CU

    const int b    = blockIdx.x;
    const int tid  = threadIdx.x;
    const int lane = tid & 63;
    const int w    = tid >> 6;
    const int wm   = w & 1;
    const int wn   = w >> 1;
    const int quad = lane >> 4;
    const int lc   = lane & 15;

    // sid: position p maps to sid[p+1]; sid[0]/sid[513] -> id 0 (Tb row 0 is all-zero)
    for (int i = tid; i < 514; i += 512) {
        int gp = i - 1;
        unsigned int id = (gp >= 0 && gp < SEQ) ? (unsigned int)cid[(size_t)b * SEQ + gp] : 0u;
        sid[i] = id * 256u;
    }

    // B fragments: 12 K-steps x 2 n-tiles (compiler may rematerialize; Wp is L2-hot)
    bf16x8 bfr[12][2];
#pragma unroll
    for (int s = 0; s < 12; ++s)
#pragma unroll
        for (int nt = 0; nt < 2; ++nt) {
            int g = wn * 2 + nt;
            bfr[s][nt] = *(const bf16x8*)(Wp + (size_t)((s * 8 + g) * 64 + lane) * 8);
        }

    int e1 = min(p1[b], p2[b]);
    int e2 = max(p1[b], p2[b]);
    if (e1 == e2) e2 = min(e1 + 1, SEQ);
    const int e1m = max(e1, 1);

    float smax[3][2];
#pragma unroll
    for (int s3 = 0; s3 < 3; ++s3) { smax[s3][0] = -1e30f; smax[s3][1] = -1e30f; }

    const char* TbB = (const char*)Tb;
    const int cc = tid & 15;   // 16-byte chunk in the 256 B row
    const int r0 = tid >> 4;   // starting row, stride 32

    __syncthreads();  // sid ready

    // Stage tile 0 (row r <-> global pos r-1 -> sid[r])
    uint4 g[5];
#pragma unroll
    for (int i = 0; i < 5; ++i) {
        int r = r0 + 32 * i;
        if (r < 130) g[i] = *(const uint4*)(TbB + sid[r] + cc * 16);
    }
#pragma unroll
    for (int i = 0; i < 5; ++i) {
        int r = r0 + 32 * i;
        if (r < 130) *(uint4*)(&xs[0][r * 136 + cc * 8]) = g[i];
    }

    for (int t = 0; t < 4; ++t) {
        __syncthreads();  // xs[t&1] ready; xs[(t+1)&1] free to overwrite

        // Issue next tile's gathers early (latency hidden under MFMA below)
        if (t < 3) {
#pragma unroll
            for (int i = 0; i < 5; ++i) {
                int r = r0 + 32 * i;
                if (r < 130) g[i] = *(const uint4*)(TbB + sid[(t + 1) * 128 + r] + cc * 16);
            }
        }

        const unsigned short* xb = xs[t & 1];
        f32x4 acc[4][2];
#pragma unroll
        for (int mt = 0; mt < 4; ++mt)
#pragma unroll
            for (int nt = 0; nt < 2; ++nt)
                acc[mt][nt] = (f32x4){0.f, 0.f, 0.f, 0.f};

#pragma unroll
        for (int s = 0; s < 12; ++s) {
            const int tap = s >> 2;
            const int eb  = (s & 3) * 32;
            bf16x8 af[4];
#pragma unroll
            for (int mt = 0; mt < 4; ++mt) {
                int r = wm * 64 + mt * 16 + lc + tap;
                af[mt] = *(const bf16x8*)(xb + r * 136 + eb + quad * 8);
            }
#pragma unroll
            for (int mt = 0; mt < 4; ++mt)
#pragma unroll
                for (int nt = 0; nt < 2; ++nt)
                    acc[mt][nt] = __builtin_amdgcn_mfma_f32_16x16x32_bf16(
                        af[mt], bfr[s][nt], acc[mt][nt], 0, 0, 0);
        }

        // Fused piecewise max-pool (bias+relu after pooling; monotone, segments non-empty)
#pragma unroll
        for (int mt = 0; mt < 4; ++mt)
#pragma unroll
            for (int reg = 0; reg < 4; ++reg) {
                int p = t * 128 + wm * 64 + mt * 16 + quad * 4 + reg;
                float a0 = (p < e1m) ? 0.f : -2e30f;
                float a1 = (p >= e1 && p < e2) ? 0.f : -2e30f;
                float a2 = (p >= e2) ? 0.f : -2e30f;
#pragma unroll
                for (int nt = 0; nt < 2; ++nt) {
                    float v = acc[mt][nt][reg];
                    smax[0][nt] = fmaxf(smax[0][nt], v + a0);
                    smax[1][nt] = fmaxf(smax[1][nt], v + a1);
                    smax[2][nt] = fmaxf(smax[2][nt], v + a2);
                }
            }

        // Write prefetched tile into the other buffer (vmcnt wait lands here)
        if (t < 3) {
#pragma unroll
            for (int i = 0; i < 5; ++i) {
                int r = r0 + 32 * i;
                if (r < 130) *(uint4*)(&xs[(t + 1) & 1][r * 136 + cc * 8]) = g[i];
            }
        }
    }

    // Quad reduction in-register (butterfly over lanes ^16, ^32)
#pragma unroll
    for (int s3 = 0; s3 < 3; ++s3)
#pragma unroll
        for (int nt = 0; nt < 2; ++nt) {
            float v = smax[s3][nt];
            v = fmaxf(v, __shfl_xor(v, 16));
            v = fmaxf(v, __shfl_xor(v, 32));
            smax[s3][nt] = v;
        }
    if (lane < 16) {
#pragma unroll
        for (int s3 = 0; s3 < 3; ++s3)
#pragma unroll
            for (int nt = 0; nt < 2; ++nt)
                pstage[wm][s3][(wn * 2 + nt) * 16 + lc] = smax[s3][nt];
    }
    __syncthreads();

    if (tid < 384) {
        int s3 = tid >> 7, f = tid & 127;
        float m = fmaxf(pstage[0][s3][f], pstage[1][s3][f]);
        pooled[tid] = fmaxf(m + cb[f], 0.f);
    }
    __syncthreads();

    // FC: 53 outputs, 4 partial dots of 96 each
    if (tid < 212) {
        int c = tid >> 2, q = tid & 3;
        const float* wrow = fcw + (size_t)c * 384 + q * 96;
        const float* pp   = pooled + q * 96;
        float sum = 0.f;
#pragma unroll 8
        for (int i = 0; i < 96; ++i) sum += wrow[i] * pp[i];
        fcred[c][q] = sum;
    }
    __syncthreads();
    if (tid < NUMC)
        out[(size_t)b * NUMC + tid] =
            fcred[tid][0] + fcred[tid][1] + fcred[tid][2] + fcred[tid][3] + fcb[tid];
}

extern "C" void kernel_launch(void* const* d_in, const int* in_sizes, int n_in,
                              void* d_out, int out_size, void* d_ws, size_t ws_size,
                              hipStream_t stream) {
    const int*   cid = (const int*)d_in[0];
    const int*   p1  = (const int*)d_in[1];
    const int*   p2  = (const int*)d_in[2];
    const float* emb = (const float*)d_in[3];
    const float* cw  = (const float*)d_in[4];
    const float* cb  = (const float*)d_in[5];
    const float* fcw = (const float*)d_in[6];
    const float* fcb = (const float*)d_in[7];
    float* out = (float*)d_out;

    // ws: Tb bf16 [VOCAB*128] (5,408,768 B) | Wp bf16 [49152] (98,304 B)
    unsigned short* Tb = (unsigned short*)d_ws;
    unsigned short* Wp = (unsigned short*)((char*)d_ws + (size_t)VOCAB * EMB * 2);

    const int n8 = VOCAB * EMB / 8;  // 338048 threads needed (>= 49152 for Wp)
    const int prep_threads = 256;
    const int prep_blocks  = (n8 + prep_threads - 1) / prep_threads;
    prep_kernel<<<prep_blocks, prep_threads, 0, stream>>>(emb, cw, Tb, Wp);
    pcnn_main<<<BATCH, 512, 0, stream>>>(cid, p1, p2, Tb, Wp, cb, fcw, fcb, out);
}

// Round 3
// 127.533 us; speedup vs baseline: 1.2337x; 1.2337x over previous
//
#include <hip/hip_runtime.h>
#include <stdint.h>

#define VOCAB 21128
#define NUMC  53
#define EMB   128
#define SEQ   512
#define BATCH 512

typedef __bf16 bf16x8 __attribute__((ext_vector_type(8)));
typedef float f32x4 __attribute__((ext_vector_type(4)));

__device__ __forceinline__ unsigned int f2bf1(float f) {
    union { float f; unsigned int u; } v; v.f = f;
    return (v.u + 0x7FFFu + ((v.u >> 16) & 1u)) >> 16;
}
__device__ __forceinline__ unsigned int pack2(float a, float b) {
    return f2bf1(a) | (f2bf1(b) << 16);
}

// Prep: emb_table fp32 -> bf16 Tb[VOCAB][128] (8 elem/thread, vectorized);
// conv_w -> Wp bf16 in per-lane B-fragment order:
// Wp[s 0..11][g 0..7][lane 0..63][j 0..7] = w[f=g*16+(lane&15)][e=kk&127][tap=kk>>7],
// kk = s*32 + (lane>>4)*8 + j
__global__ void prep_kernel(const float* __restrict__ emb, const float* __restrict__ cw,
                            unsigned short* __restrict__ Tb, unsigned short* __restrict__ Wp) {
    int idx = blockIdx.x * blockDim.x + threadIdx.x;
    const int n8 = VOCAB * EMB / 8;  // 338048
    if (idx < n8) {
        const float4* src = (const float4*)emb + (size_t)idx * 2;
        float4 a = src[0], b = src[1];
        uint4 o;
        o.x = pack2(a.x, a.y);
        o.y = pack2(a.z, a.w);
        o.z = pack2(b.x, b.y);
        o.w = pack2(b.z, b.w);
        *(uint4*)(Tb + (size_t)idx * 8) = o;
    }
    if (idx < 12 * 8 * 64 * 8) {
        int j = idx & 7, l = (idx >> 3) & 63, g = (idx >> 9) & 7, s = idx >> 12;
        int kk = s * 32 + (l >> 4) * 8 + j;
        int f = g * 16 + (l & 15);
        int tap = kk >> 7, e = kk & 127;
        Wp[idx] = (unsigned short)f2bf1(cw[(f * EMB + e) * 3 + tap]);
    }
}

// One block per batch row. 512 threads = 8 waves, wave w: wm=w&1 (64-pos half),
// wn=w>>1 (32-filter quarter). 4 l-tiles of 128 positions, double-buffered LDS
// with register prefetch of the next tile's gather issued BEFORE the MFMA loop.
// NOTE: (512,2) bounds — (512,4) forced VGPR=64 and spilled 245 MB to scratch (R2).
__launch_bounds__(512, 2)
__global__ void pcnn_main(const int* __restrict__ cid, const int* __restrict__ p1,
                          const int* __restrict__ p2,
                          const unsigned short* __restrict__ Tb,
                          const unsigned short* __restrict__ Wp,
                          const float* __restrict__ cb, const float* __restrict__ fcw,
                          const float* __restrict__ fcb, float* __restrict__ out) {
    // x-tile: 130 rows (1-halo) x 128 emb bf16, rows padded to 136 hw (272 B)
    __shared__ __align__(16) unsigned short xs[2][130 * 136];  // 2 x 35,360 B
    __shared__ unsigned int sid[514];                          // id*256 byte offsets, OOB->row 0 (zeros)
    __shared__ float pstage[2][3][128];
    __shared__ float pooled[384];
    __shared__ float fcred[NUMC][4];
    // total ~78.2 KB -> 2 blocks/CU by LDS

    const int b    = blockIdx.x;
    const int tid  = threadIdx.x;
    const int lane = tid & 63;
    const int w    = tid >> 6;
    const int wm   = w & 1;
    const int wn   = w >> 1;
    const int quad = lane >> 4;
    const int lc   = lane & 15;

    // sid: position p maps to sid[p+1]; sid[0]/sid[513] -> id 0 (Tb row 0 is all-zero)
    for (int i = tid; i < 514; i += 512) {
        int gp = i - 1;
        unsigned int id = (gp >= 0 && gp < SEQ) ? (unsigned int)cid[(size_t)b * SEQ + gp] : 0u;
        sid[i] = id * 256u;
    }

    // B fragments: 12 K-steps x 2 n-tiles (compiler may rematerialize; Wp is L2-hot)
    bf16x8 bfr[12][2];
#pragma unroll
    for (int s = 0; s < 12; ++s)
#pragma unroll
        for (int nt = 0; nt < 2; ++nt) {
            int g = wn * 2 + nt;
            bfr[s][nt] = *(const bf16x8*)(Wp + (size_t)((s * 8 + g) * 64 + lane) * 8);
        }

    int e1 = min(p1[b], p2[b]);
    int e2 = max(p1[b], p2[b]);
    if (e1 == e2) e2 = min(e1 + 1, SEQ);
    const int e1m = max(e1, 1);

    float smax[3][2];
#pragma unroll
    for (int s3 = 0; s3 < 3; ++s3) { smax[s3][0] = -1e30f; smax[s3][1] = -1e30f; }

    const char* TbB = (const char*)Tb;
    const int cc = tid & 15;   // 16-byte chunk in the 256 B row
    const int r0 = tid >> 4;   // starting row, stride 32

    __syncthreads();  // sid ready

    // Stage tile 0 (row r <-> global pos r-1 -> sid[r])
    uint4 g[5];
#pragma unroll
    for (int i = 0; i < 5; ++i) {
        int r = r0 + 32 * i;
        if (r < 130) g[i] = *(const uint4*)(TbB + sid[r] + cc * 16);
    }
#pragma unroll
    for (int i = 0; i < 5; ++i) {
        int r = r0 + 32 * i;
        if (r < 130) *(uint4*)(&xs[0][r * 136 + cc * 8]) = g[i];
    }

    for (int t = 0; t < 4; ++t) {
        __syncthreads();  // xs[t&1] ready; xs[(t+1)&1] free to overwrite

        // Issue next tile's gathers early (latency hidden under MFMA below)
        if (t < 3) {
#pragma unroll
            for (int i = 0; i < 5; ++i) {
                int r = r0 + 32 * i;
                if (r < 130) g[i] = *(const uint4*)(TbB + sid[(t + 1) * 128 + r] + cc * 16);
            }
        }

        const unsigned short* xb = xs[t & 1];
        f32x4 acc[4][2];
#pragma unroll
        for (int mt = 0; mt < 4; ++mt)
#pragma unroll
            for (int nt = 0; nt < 2; ++nt)
                acc[mt][nt] = (f32x4){0.f, 0.f, 0.f, 0.f};

#pragma unroll
        for (int s = 0; s < 12; ++s) {
            const int tap = s >> 2;
            const int eb  = (s & 3) * 32;
            bf16x8 af[4];
#pragma unroll
            for (int mt = 0; mt < 4; ++mt) {
                int r = wm * 64 + mt * 16 + lc + tap;
                af[mt] = *(const bf16x8*)(xb + r * 136 + eb + quad * 8);
            }
#pragma unroll
            for (int mt = 0; mt < 4; ++mt)
#pragma unroll
                for (int nt = 0; nt < 2; ++nt)
                    acc[mt][nt] = __builtin_amdgcn_mfma_f32_16x16x32_bf16(
                        af[mt], bfr[s][nt], acc[mt][nt], 0, 0, 0);
        }

        // Fused piecewise max-pool (bias+relu after pooling; monotone, segments non-empty)
#pragma unroll
        for (int mt = 0; mt < 4; ++mt)
#pragma unroll
            for (int reg = 0; reg < 4; ++reg) {
                int p = t * 128 + wm * 64 + mt * 16 + quad * 4 + reg;
                float a0 = (p < e1m) ? 0.f : -2e30f;
                float a1 = (p >= e1 && p < e2) ? 0.f : -2e30f;
                float a2 = (p >= e2) ? 0.f : -2e30f;
#pragma unroll
                for (int nt = 0; nt < 2; ++nt) {
                    float v = acc[mt][nt][reg];
                    smax[0][nt] = fmaxf(smax[0][nt], v + a0);
                    smax[1][nt] = fmaxf(smax[1][nt], v + a1);
                    smax[2][nt] = fmaxf(smax[2][nt], v + a2);
                }
            }

        // Write prefetched tile into the other buffer (vmcnt wait lands here)
        if (t < 3) {
#pragma unroll
            for (int i = 0; i < 5; ++i) {
                int r = r0 + 32 * i;
                if (r < 130) *(uint4*)(&xs[(t + 1) & 1][r * 136 + cc * 8]) = g[i];
            }
        }
    }

    // Quad reduction in-register (butterfly over lanes ^16, ^32)
#pragma unroll
    for (int s3 = 0; s3 < 3; ++s3)
#pragma unroll
        for (int nt = 0; nt < 2; ++nt) {
            float v = smax[s3][nt];
            v = fmaxf(v, __shfl_xor(v, 16));
            v = fmaxf(v, __shfl_xor(v, 32));
            smax[s3][nt] = v;
        }
    if (lane < 16) {
#pragma unroll
        for (int s3 = 0; s3 < 3; ++s3)
#pragma unroll
            for (int nt = 0; nt < 2; ++nt)
                pstage[wm][s3][(wn * 2 + nt) * 16 + lc] = smax[s3][nt];
    }
    __syncthreads();

    if (tid < 384) {
        int s3 = tid >> 7, f = tid & 127;
        float m = fmaxf(pstage[0][s3][f], pstage[1][s3][f]);
        pooled[tid] = fmaxf(m + cb[f], 0.f);
    }
    __syncthreads();

    // FC: 53 outputs, 4 partial dots of 96 each
    if (tid < 212) {
        int c = tid >> 2, q = tid & 3;
        const float* wrow = fcw + (size_t)c * 384 + q * 96;
        const float* pp   = pooled + q * 96;
        float sum = 0.f;
#pragma unroll 8
        for (int i = 0; i < 96; ++i) sum += wrow[i] * pp[i];
        fcred[c][q] = sum;
    }
    __syncthreads();
    if (tid < NUMC)
        out[(size_t)b * NUMC + tid] =
            fcred[tid][0] + fcred[tid][1] + fcred[tid][2] + fcred[tid][3] + fcb[tid];
}

extern "C" void kernel_launch(void* const* d_in, const int* in_sizes, int n_in,
                              void* d_out, int out_size, void* d_ws, size_t ws_size,
                              hipStream_t stream) {
    const int*   cid = (const int*)d_in[0];
    const int*   p1  = (const int*)d_in[1];
    const int*   p2  = (const int*)d_in[2];
    const float* emb = (const float*)d_in[3];
    const float* cw  = (const float*)d_in[4];
    const float* cb  = (const float*)d_in[5];
    const float* fcw = (const float*)d_in[6];
    const float* fcb = (const float*)d_in[7];
    float* out = (float*)d_out;

    // ws: Tb bf16 [VOCAB*128] (5,408,768 B) | Wp bf16 [49152] (98,304 B)
    unsigned short* Tb = (unsigned short*)d_ws;
    unsigned short* Wp = (unsigned short*)((char*)d_ws + (size_t)VOCAB * EMB * 2);

    const int n8 = VOCAB * EMB / 8;
    const int prep_threads = 256;
    const int prep_blocks  = (n8 + prep_threads - 1) / prep_threads;
    prep_kernel<<<prep_blocks, prep_threads, 0, stream>>>(emb, cw, Tb, Wp);
    pcnn_main<<<BATCH, 512, 0, stream>>>(cid, p1, p2, Tb, Wp, cb, fcw, fcb, out);
}